// Round 7
// baseline (1797.972 us; speedup 1.0000x reference)
//
#include <hip/hip_runtime.h>
#include <math.h>

#define DM 768
#define NH 12
#define DK 64
#define DFF 3072
#define BB 2
#define SS 2048
#define NL 2

typedef __attribute__((ext_vector_type(8))) short short8;
typedef __attribute__((ext_vector_type(4))) float f32x4;

__device__ inline unsigned short f2bf(float f) {
    unsigned int u = __float_as_uint(f);
    u += 0x7fffu + ((u >> 16) & 1u);
    return (unsigned short)(u >> 16);
}
__device__ inline float bf2f(unsigned short h) {
    return __uint_as_float(((unsigned int)h) << 16);
}

#define GL16(g, l) __builtin_amdgcn_global_load_lds( \
    (const __attribute__((address_space(1))) void*)(g), \
    (__attribute__((address_space(3))) void*)(l), 16, 0, 0)

// ---------------- embed + positional (f32 + bf16 outputs) ----------------
__global__ __launch_bounds__(256) void embed_kernel(
    const int* __restrict__ toks, const float* __restrict__ emb,
    const float* __restrict__ pos, float* __restrict__ x,
    unsigned short* __restrict__ xb)
{
    int rs = blockIdx.x;
    int s = rs & (SS - 1);
    int tok = toks[rs];
    int t = threadIdx.x;
    const float* e = emb + (size_t)tok * DM;
    const float* p = pos + (size_t)s * DM;
    float* xr = x + (size_t)rs * DM;
    unsigned short* xbr = xb + (size_t)rs * DM;
#pragma unroll
    for (int i = 0; i < 3; ++i) {
        int c = t + 256 * i;
        float v = e[c] + p[c];
        xr[c] = v;
        xbr[c] = f2bf(v);
    }
}

// ---------------- batched weight transpose-convert, BOTH layers, 1 launch ---
__global__ __launch_bounds__(256) void prep_weights(
    const float* __restrict__ wq, const float* __restrict__ wk,
    const float* __restrict__ wv, const float* __restrict__ wo,
    const float* __restrict__ w1, const float* __restrict__ w2,
    unsigned short* __restrict__ wt)
{
    __shared__ float tile[32][33];
    int id = blockIdx.x;
    int l = id / 6912; id -= l * 6912;
    unsigned short* wtl = wt + (size_t)l * 7077888;
    const float* src; unsigned short* dst; int Kd, Nd, nt, kt;
    if (id < 2304) {
        int m = id / 576, r = id % 576;
        src = ((m == 0) ? wq : (m == 1) ? wk : (m == 2) ? wv : wo) + (size_t)l * DM * DM;
        dst = wtl + (size_t)m * 589824;
        Kd = 768; Nd = 768; nt = r / 24; kt = r % 24;
    } else if (id < 4608) {
        int r = id - 2304;
        src = w1 + (size_t)l * DM * DFF; dst = wtl + 2359296; Kd = 768; Nd = 3072;
        nt = r / 24; kt = r % 24;
    } else {
        int r = id - 4608;
        src = w2 + (size_t)l * DFF * DM; dst = wtl + 4718592; Kd = 3072; Nd = 768;
        nt = r / 96; kt = r % 96;
    }
    int n0 = nt * 32, k0 = kt * 32;
    int c = threadIdx.x & 31, rr = threadIdx.x >> 5;
#pragma unroll
    for (int i = 0; i < 32; i += 8)
        tile[rr + i][c] = src[(size_t)(k0 + rr + i) * Nd + n0 + c];
    __syncthreads();
#pragma unroll
    for (int i = 0; i < 32; i += 8)
        dst[(size_t)(n0 + rr + i) * Kd + k0 + c] = f2bf(tile[c][rr + i]);
}

// ---------------- V transpose: vb[b*S+s][DM] bf16 -> vt[b][DM][S] bf16 ------
__global__ __launch_bounds__(256) void transpose_v(
    const unsigned short* __restrict__ vb, unsigned short* __restrict__ vt)
{
    __shared__ unsigned short tile[32][33];
    int c0 = blockIdx.x * 32;
    int r0 = blockIdx.y * 32;
    int c = threadIdx.x & 31, rr = threadIdx.x >> 5;
#pragma unroll
    for (int i = 0; i < 32; i += 8)
        tile[rr + i][c] = vb[(size_t)(r0 + rr + i) * DM + c0 + c];
    __syncthreads();
    int b = r0 >> 11;
    int s0 = r0 & 2047;
#pragma unroll
    for (int i = 0; i < 32; i += 8)
        vt[((size_t)b * DM + c0 + rr + i) * SS + s0 + c] = tile[c][rr + i];
}

// ---------------- MFMA GEMM: C[M,N] = A[M,K](bf16) @ Bt[N,K](bf16)^T --------
// 128x128 tile, BK=64, swizzled LDS (conflict-free ds_read_b128), 4 waves.
// OUT_MODE: 0=f32 split-K partial (blockIdx.z slice), 1=bf16, 2=bf16+relu,
//           4=bf16 into 3 consecutive [4096][768] mats
template<int OUT_MODE>
__global__ __launch_bounds__(256) void gemm_bt(
    const unsigned short* __restrict__ A, const unsigned short* __restrict__ Bt,
    const float* __restrict__ bias, void* __restrict__ Cv,
    int K, int lda, int ldb, int ldc)
{
    __shared__ unsigned short As[128 * 64];   // 16KB, 128B rows, chunk-swizzled
    __shared__ unsigned short Bs[128 * 64];   // 16KB
    const int t = threadIdx.x;
    const int row0 = blockIdx.y * 128;
    const int col0 = blockIdx.x * 128;
    const int z = (OUT_MODE == 0) ? blockIdx.z : 0;
    if (OUT_MODE == 0) { A += (size_t)z * K; Bt += (size_t)z * K; }
    const int lane = t & 63, wid = t >> 6;
    const int wr = wid >> 1, wc = wid & 1;
    const int half = lane >> 4, lr = lane & 15;
    f32x4 acc[4][4] = {};

    for (int k0 = 0; k0 < K; k0 += 64) {
        // stage A,B tiles: pre-swizzled source chunk, linear LDS dest (rule #21)
#pragma unroll
        for (int r_ = 0; r_ < 4; ++r_) {
            int o_ = r_ * 4096 + t * 16;
            int row_ = o_ >> 7;                 // 0..127
            int cp_ = (o_ >> 4) & 7;            // 16B chunk within 128B row
            int gk_ = (cp_ ^ (row_ & 7)) << 3;  // swizzled k-offset (ushorts)
            GL16(A + (size_t)(row0 + row_) * lda + k0 + gk_, (char*)As + o_);
            GL16(Bt + (size_t)(col0 + row_) * ldb + k0 + gk_, (char*)Bs + o_);
        }
        __syncthreads();
#pragma unroll
        for (int kk = 0; kk < 2; ++kk) {
            short8 a_[4], b_[4];
#pragma unroll
            for (int m = 0; m < 4; ++m) {
                int row_ = wr * 64 + m * 16 + lr;
                a_[m] = *(const short8*)&As[row_ * 64 + (((kk * 4 + half) ^ (row_ & 7)) << 3)];
            }
#pragma unroll
            for (int n = 0; n < 4; ++n) {
                int row_ = wc * 64 + n * 16 + lr;
                b_[n] = *(const short8*)&Bs[row_ * 64 + (((kk * 4 + half) ^ (row_ & 7)) << 3)];
            }
#pragma unroll
            for (int m = 0; m < 4; ++m)
#pragma unroll
                for (int n = 0; n < 4; ++n)
                    acc[m][n] = __builtin_amdgcn_mfma_f32_16x16x32_bf16(a_[m], b_[n], acc[m][n], 0, 0, 0);
        }
        __syncthreads();
    }

#pragma unroll
    for (int m = 0; m < 4; ++m) {
#pragma unroll
        for (int n = 0; n < 4; ++n) {
            const int cidx = col0 + wc * 64 + n * 16 + lr;
            const float bv = bias ? bias[cidx] : 0.0f;
#pragma unroll
            for (int j = 0; j < 4; ++j) {
                const int r = row0 + wr * 64 + m * 16 + half * 4 + j;
                float v = acc[m][n][j] + bv;
                if (OUT_MODE == 2) v = fmaxf(v, 0.0f);
                if (OUT_MODE == 0) {
                    ((float*)Cv)[((size_t)z * 4096 + r) * ldc + cidx] = v;
                } else if (OUT_MODE == 4) {
                    int mi = (cidx >= 1536) ? 2 : (cidx >= 768 ? 1 : 0);
                    int cl = cidx - mi * 768;
                    ((unsigned short*)Cv)[((size_t)mi * 4096 + r) * 768 + cl] = f2bf(v);
                } else {
                    ((unsigned short*)Cv)[(size_t)r * ldc + cidx] = f2bf(v);
                }
            }
        }
    }
}

// ---------------- fused attention v4: QBLK=64, 2-pass, dbuf K/V, 80KB LDS ---
// 768 blocks; id&7 = XCD, 3 heads/XCD (K/V L2-resident). Pass A: row sums.
// Pass B: normalized E (reg rinv) -> NT P-write + PV. 4 waves, 2 blocks/CU.
__global__ __launch_bounds__(256) void attn_fused(
    const unsigned short* __restrict__ qg, const unsigned short* __restrict__ kg,
    const unsigned short* __restrict__ vt, const int* __restrict__ amask,
    float* __restrict__ attnL, unsigned short* __restrict__ cb)
{
    __shared__ unsigned short Ks[2][128 * 64];   // 2x16KB [krow][dk], swizzled
    __shared__ unsigned short Vs[2][64 * 128];   // 2x16KB [d][s], swizzled
    __shared__ unsigned short Es[64 * 128];      // 16KB [qrow][kcol]; aliased as redsum between passes

    const int t = threadIdx.x;
    const int id = blockIdx.x;              // 0..767
    const int xcd = id & 7, idx = id >> 3;  // idx 0..95
    const int bh = xcd * 3 + (idx >> 5);    // 24 heads, 3 per XCD
    const int qt = idx & 31;
    const int b = bh / NH, h = bh % NH;
    const int q0 = qt * 64;
    const int lane = t & 63, w = t >> 6;
    const int half = lane >> 4, lr = lane & 15;
    const int* am = amask + b * SS;

    // Q A-frags: afq[m][ks] -> rows q0+m*16+lr, k = ks*32 + half*8
    const unsigned short* qbase = qg + ((size_t)b * SS + q0 + lr) * DM + h * DK + half * 8;
    short8 afq[4][2];
#pragma unroll
    for (int m = 0; m < 4; ++m) {
        afq[m][0] = *(const short8*)(qbase + m * 16 * DM);
        afq[m][1] = *(const short8*)(qbase + m * 16 * DM + 32);
    }

    const unsigned short* Kg = kg + (size_t)b * SS * DM + h * DK;
    const unsigned short* Vg = vt + ((size_t)b * DM + h * DK) * SS;

#define STAGE_K(kt, buf) { \
    _Pragma("unroll") \
    for (int r_ = 0; r_ < 4; ++r_) { \
        int o_ = r_ * 4096 + t * 16; \
        int krow_ = o_ >> 7; \
        int cp_ = (o_ >> 4) & 7; \
        GL16(Kg + (size_t)((kt) * 128 + krow_) * DM + ((cp_ ^ (krow_ & 7)) << 3), (char*)Ks[buf] + o_); \
    } }
#define STAGE_V(kt, buf) { \
    _Pragma("unroll") \
    for (int r_ = 0; r_ < 4; ++r_) { \
        int o_ = r_ * 4096 + t * 16; \
        int d_ = o_ >> 8; \
        int cp_ = (o_ >> 4) & 15; \
        GL16(Vg + (size_t)d_ * SS + (kt) * 128 + ((cp_ ^ (d_ & 7)) << 3), (char*)Vs[buf] + o_); \
    } }

    // ================= pass A: row sums =================
    float vsum[4][4] = {};
    STAGE_K(0, 0);
    for (int kt = 0; kt < 16; ++kt) {
        asm volatile("s_waitcnt vmcnt(0)" ::: "memory");
        __builtin_amdgcn_s_barrier();
        if (kt < 15) STAGE_K(kt + 1, (kt + 1) & 1);
        const char* kbuf = (const char*)Ks[kt & 1];
#pragma unroll
        for (int nn = 0; nn < 2; ++nn) {
            const int krl = w * 32 + nn * 16 + lr;
            const char* kr = kbuf + krl * 128;
            const int ksw = krl & 7;
            short8 bk0 = *(const short8*)(kr + ((half ^ ksw) << 4));
            short8 bk1 = *(const short8*)(kr + (((4 + half) ^ ksw) << 4));
            const int kpos = kt * 128 + krl;
            const bool pad = (am[kpos] == 0);
#pragma unroll
            for (int m = 0; m < 4; ++m) {
                f32x4 s = {};
                s = __builtin_amdgcn_mfma_f32_16x16x32_bf16(afq[m][0], bk0, s, 0, 0, 0);
                s = __builtin_amdgcn_mfma_f32_16x16x32_bf16(afq[m][1], bk1, s, 0, 0, 0);
#pragma unroll
                for (int j = 0; j < 4; ++j) {
                    int qpos = q0 + m * 16 + half * 4 + j;
                    if (pad || (kpos > qpos))   // FAITHFUL: keep where pad||future
                        vsum[m][j] += __expf(0.125f * s[j]);
                }
            }
        }
    }
    // prefetch pass-B tile 0 while reducing (Ks[0] free: last read was kt=14)
    STAGE_K(0, 0);
    STAGE_V(0, 0);
    __syncthreads();

    // cross-lane + cross-wave reduce via Es-aliased scratch; rinv -> registers
    float* red = (float*)Es;     // [0..255]: per-wave sums, [256..319]: inv
#pragma unroll
    for (int m = 0; m < 4; ++m)
#pragma unroll
        for (int j = 0; j < 4; ++j) {
            vsum[m][j] += __shfl_xor(vsum[m][j], 1, 64);
            vsum[m][j] += __shfl_xor(vsum[m][j], 2, 64);
            vsum[m][j] += __shfl_xor(vsum[m][j], 4, 64);
            vsum[m][j] += __shfl_xor(vsum[m][j], 8, 64);
        }
    if (lr == 0) {
#pragma unroll
        for (int m = 0; m < 4; ++m)
#pragma unroll
            for (int j = 0; j < 4; ++j)
                red[w * 64 + m * 16 + half * 4 + j] = vsum[m][j];
    }
    __syncthreads();
    if (t < 64) {
        float rs = red[t] + red[64 + t] + red[128 + t] + red[192 + t];
        red[256 + t] = (rs > 0.0f) ? 1.0f / rs : 0.0f;
    }
    __syncthreads();
    float rinv[4][4];
#pragma unroll
    for (int m = 0; m < 4; ++m)
#pragma unroll
        for (int j = 0; j < 4; ++j)
            rinv[m][j] = red[256 + m * 16 + half * 4 + j];
    __syncthreads();   // rinv in regs; Es area may now be overwritten

    // ================= pass B: normalized E -> P + PV =================
    f32x4 ctxa[4] = {};
    float* ab = attnL + ((size_t)bh * SS + q0) * SS;
    for (int kt = 0; kt < 16; ++kt) {
        if (kt == 0) {
            asm volatile("s_waitcnt vmcnt(0)" ::: "memory");
        } else {
            asm volatile("s_waitcnt vmcnt(8)" ::: "memory");  // 8 stage loads done, P-stores in flight
        }
        __builtin_amdgcn_s_barrier();
        if (kt < 15) { STAGE_K(kt + 1, (kt + 1) & 1); STAGE_V(kt + 1, (kt + 1) & 1); }
        const char* kbuf = (const char*)Ks[kt & 1];
#pragma unroll
        for (int nn = 0; nn < 2; ++nn) {
            const int krl = w * 32 + nn * 16 + lr;
            const char* kr = kbuf + krl * 128;
            const int ksw = krl & 7;
            short8 bk0 = *(const short8*)(kr + ((half ^ ksw) << 4));
            short8 bk1 = *(const short8*)(kr + (((4 + half) ^ ksw) << 4));
            const int kpos = kt * 128 + krl;
            const bool pad = (am[kpos] == 0);
#pragma unroll
            for (int m = 0; m < 4; ++m) {
                f32x4 s = {};
                s = __builtin_amdgcn_mfma_f32_16x16x32_bf16(afq[m][0], bk0, s, 0, 0, 0);
                s = __builtin_amdgcn_mfma_f32_16x16x32_bf16(afq[m][1], bk1, s, 0, 0, 0);
#pragma unroll
                for (int j = 0; j < 4; ++j) {
                    int row = m * 16 + half * 4 + j;
                    int qpos = q0 + row;
                    bool keep = pad || (kpos > qpos);
                    float e = keep ? __expf(0.125f * s[j]) * rinv[m][j] : 0.0f;
                    *((unsigned short*)((char*)Es + row * 256 + ((krl * 2) ^ ((row & 7) << 4)))) = f2bf(e);
                }
            }
        }
        asm volatile("s_waitcnt lgkmcnt(0)" ::: "memory");   // E-writes visible
        __builtin_amdgcn_s_barrier();

        // PV: ctx += E[64x128] @ V[128x64]; wave w owns d-cols w*16..+15
        const char* vbuf = (const char*)Vs[kt & 1];
#pragma unroll
        for (int ks = 0; ks < 4; ++ks) {
            const int dl = w * 16 + lr;
            const int cv = ks * 4 + half;
            short8 bv = *(const short8*)(vbuf + dl * 256 + ((cv ^ (dl & 7)) << 4));
#pragma unroll
            for (int m = 0; m < 4; ++m) {
                short8 ae = *(const short8*)((const char*)Es + (m * 16 + lr) * 256 +
                                             ((ks * 64 + half * 16) ^ ((lr & 7) << 4)));
                ctxa[m] = __builtin_amdgcn_mfma_f32_16x16x32_bf16(ae, bv, ctxa[m], 0, 0, 0);
            }
        }

        // P-write: 256 threads cover 64 rows x 4 chunk-groups (32 f32 each), NT
        {
            const int prow = t >> 2, pg = t & 3;
            const char* erow = (const char*)Es + prow * 256;
            const int swz = (prow & 7) << 4;
            float* drow = ab + (size_t)prow * SS + kt * 128;
#pragma unroll
            for (int c = 0; c < 4; ++c) {
                const int chunk = pg * 4 + c;
                short8 ev = *(const short8*)(erow + ((chunk * 16) ^ swz));
                float* dst = drow + chunk * 8;
                f32x4 o0, o1;
                o0[0] = bf2f((unsigned short)ev[0]); o0[1] = bf2f((unsigned short)ev[1]);
                o0[2] = bf2f((unsigned short)ev[2]); o0[3] = bf2f((unsigned short)ev[3]);
                o1[0] = bf2f((unsigned short)ev[4]); o1[1] = bf2f((unsigned short)ev[5]);
                o1[2] = bf2f((unsigned short)ev[6]); o1[3] = bf2f((unsigned short)ev[7]);
                __builtin_nontemporal_store(o0, (f32x4*)dst);
                __builtin_nontemporal_store(o1, (f32x4*)(dst + 4));
            }
        }
    }

    // ctx write (already normalized)
#pragma unroll
    for (int m = 0; m < 4; ++m)
#pragma unroll
        for (int j = 0; j < 4; ++j) {
            int row = m * 16 + half * 4 + j;
            cb[((size_t)b * SS + q0 + row) * DM + h * DK + w * 16 + lr] = f2bf(ctxa[m][j]);
        }
#undef STAGE_K
#undef STAGE_V
}

// ------- residual add (two f32 split-K partials + opt bias) + layernorm ----
__global__ __launch_bounds__(256) void add_ln_kernel(
    const float* __restrict__ p0, const float* __restrict__ p1,
    const float* __restrict__ bias, const float* __restrict__ xin,
    const float* __restrict__ g, const float* __restrict__ bta,
    float* __restrict__ xout, unsigned short* __restrict__ xbout)
{
    int row = blockIdx.x;
    int t = threadIdx.x;
    const float* a0 = p0 + (size_t)row * DM;
    const float* a1 = p1 + (size_t)row * DM;
    const float* xr = xin + (size_t)row * DM;
    float* orow = xout + (size_t)row * DM;
    unsigned short* obr = xbout + (size_t)row * DM;
    __shared__ float red[256];
    float v[3];
    float sum = 0.0f;
#pragma unroll
    for (int i = 0; i < 3; ++i) {
        int c = t + 256 * i;
        v[i] = a0[c] + a1[c] + xr[c] + (bias ? bias[c] : 0.0f);
        sum += v[i];
    }
    red[t] = sum;
    __syncthreads();
    for (int s = 128; s > 0; s >>= 1) {
        if (t < s) red[t] += red[t + s];
        __syncthreads();
    }
    float mean = red[0] * (1.0f / DM);
    __syncthreads();
    float sq = 0.0f;
#pragma unroll
    for (int i = 0; i < 3; ++i) {
        float d = v[i] - mean;
        sq += d * d;
    }
    red[t] = sq;
    __syncthreads();
    for (int s = 128; s > 0; s >>= 1) {
        if (t < s) red[t] += red[t + s];
        __syncthreads();
    }
    float inv = 1.0f / sqrtf(red[0] * (1.0f / DM) + 1e-5f);
#pragma unroll
    for (int i = 0; i < 3; ++i) {
        int c = t + 256 * i;
        float ov = (v[i] - mean) * inv * g[c] + bta[c];
        orow[c] = ov;
        obr[c] = f2bf(ov);
    }
}

extern "C" void kernel_launch(void* const* d_in, const int* in_sizes, int n_in,
                              void* d_out, int out_size, void* d_ws, size_t ws_size,
                              hipStream_t stream)
{
    const int*   toks  = (const int*)d_in[0];
    const int*   amask = (const int*)d_in[1];
    const float* emb   = (const float*)d_in[2];
    const float* pos   = (const float*)d_in[3];
    const float* wq    = (const float*)d_in[4];
    const float* wk    = (const float*)d_in[5];
    const float* wv    = (const float*)d_in[6];
    const float* wo    = (const float*)d_in[7];
    const float* ln1g  = (const float*)d_in[8];
    const float* ln1b  = (const float*)d_in[9];
    const float* w1    = (const float*)d_in[10];
    const float* b1    = (const float*)d_in[11];
    const float* w2    = (const float*)d_in[12];
    const float* b2    = (const float*)d_in[13];
    const float* ln2g  = (const float*)d_in[14];
    const float* ln2b  = (const float*)d_in[15];

    float* out = (float*)d_out;
    char*  wsb = (char*)d_ws;

    const size_t ROWS = (size_t)BB * SS;                 // 4096
    const size_t XSZ  = ROWS * DM;                       // 3,145,728
    const size_t ATTN_L = (size_t)BB * NH * SS * SS;     // 100,663,296

    float*          x    = (float*)(wsb);                          // 12.58 MB
    unsigned short* xb   = (unsigned short*)(wsb + 12582912);      // 6.29 MB
    unsigned short* qb   = (unsigned short*)(wsb + 18874368);      // 6.29 MB (QKV out 0)
    unsigned short* kbuf = (unsigned short*)(wsb + 25165824);      // 6.29 MB (QKV out 1)
    unsigned short* vb   = (unsigned short*)(wsb + 31457280);      // 6.29 MB (QKV out 2)
    unsigned short* cb   = (unsigned short*)(wsb + 37748736);      // 6.29 MB
    float*          p0   = (float*)(wsb + 44040192);               // 25.17 MB (2 split-K slabs)
    unsigned short* vt   = (unsigned short*)(wsb + 69206016);      // aliases ffb
    unsigned short* ffb  = (unsigned short*)(wsb + 69206016);      // 25.17 MB
    unsigned short* wt   = (unsigned short*)(wsb + 94371840);      // 28.31 MB (both layers)

    float* attn_out = out + XSZ;

    embed_kernel<<<ROWS, 256, 0, stream>>>(toks, emb, pos, x, xb);
    prep_weights<<<13824, 256, 0, stream>>>(wq, wk, wv, wo, w1, w2, wt);

    for (int l = 0; l < NL; ++l) {
        unsigned short* QKVT = wt + (size_t)l * 7077888;
        unsigned short* WOT  = QKVT + 1769472;
        unsigned short* W1T  = QKVT + 2359296;
        unsigned short* W2T  = QKVT + 4718592;

        // merged QKV projection: N=2304 -> qb | kbuf | vb (row-major bf16)
        gemm_bt<4><<<dim3(18, 32), 256, 0, stream>>>(xb, QKVT, nullptr, qb, DM, DM, DM, DM);
        transpose_v<<<dim3(24, 128), 256, 0, stream>>>(vb, vt);

        float* attnL = attn_out + (size_t)l * ATTN_L;
        attn_fused<<<768, 256, 0, stream>>>(qb, kbuf, vt, amask, attnL, cb);

        // output projection (split-K=2, f32 partials) + LN1
        gemm_bt<0><<<dim3(6, 32, 2), 256, 0, stream>>>(cb, WOT, nullptr, p0, 384, DM, DM, DM);
        add_ln_kernel<<<ROWS, 256, 0, stream>>>(p0, p0 + XSZ, nullptr, x,
                                                ln1g + l * DM, ln1b + l * DM, x, xb);

        // FFN: W1+relu, W2 (split-K=2) + LN2 (bias b2 folded into LN)
        gemm_bt<2><<<dim3(24, 32), 256, 0, stream>>>(xb, W1T, b1 + (size_t)l * DFF, ffb, DM, DM, DM, DFF);
        gemm_bt<0><<<dim3(6, 32, 2), 256, 0, stream>>>(ffb, W2T, nullptr, p0, 1536, DFF, DFF, DM);

        float* xdst = (l == NL - 1) ? out : x;
        add_ln_kernel<<<ROWS, 256, 0, stream>>>(p0, p0 + XSZ, b2 + (size_t)l * DM, x,
                                                ln2g + l * DM, ln2b + l * DM, xdst, xb);
    }
}

// Round 8
// 759.970 us; speedup vs baseline: 2.3658x; 2.3658x over previous
//
#include <hip/hip_runtime.h>
#include <math.h>

#define DM 768
#define NH 12
#define DK 64
#define DFF 3072
#define BB 2
#define SS 2048
#define NL 2

typedef __attribute__((ext_vector_type(8))) short short8;
typedef __attribute__((ext_vector_type(4))) float f32x4;

__device__ inline unsigned short f2bf(float f) {
    unsigned int u = __float_as_uint(f);
    u += 0x7fffu + ((u >> 16) & 1u);
    return (unsigned short)(u >> 16);
}
__device__ inline float bf2f(unsigned short h) {
    return __uint_as_float(((unsigned int)h) << 16);
}

#define GL16(g, l) __builtin_amdgcn_global_load_lds( \
    (const __attribute__((address_space(1))) void*)(g), \
    (__attribute__((address_space(3))) void*)(l), 16, 0, 0)

// ---------------- embed + positional (f32 + bf16 outputs) ----------------
__global__ __launch_bounds__(256) void embed_kernel(
    const int* __restrict__ toks, const float* __restrict__ emb,
    const float* __restrict__ pos, float* __restrict__ x,
    unsigned short* __restrict__ xb)
{
    int rs = blockIdx.x;
    int s = rs & (SS - 1);
    int tok = toks[rs];
    int t = threadIdx.x;
    const float* e = emb + (size_t)tok * DM;
    const float* p = pos + (size_t)s * DM;
    float* xr = x + (size_t)rs * DM;
    unsigned short* xbr = xb + (size_t)rs * DM;
#pragma unroll
    for (int i = 0; i < 3; ++i) {
        int c = t + 256 * i;
        float v = e[c] + p[c];
        xr[c] = v;
        xbr[c] = f2bf(v);
    }
}

// ---------------- batched weight transpose-convert, BOTH layers, 1 launch ---
__global__ __launch_bounds__(256) void prep_weights(
    const float* __restrict__ wq, const float* __restrict__ wk,
    const float* __restrict__ wv, const float* __restrict__ wo,
    const float* __restrict__ w1, const float* __restrict__ w2,
    unsigned short* __restrict__ wt)
{
    __shared__ float tile[32][33];
    int id = blockIdx.x;
    int l = id / 6912; id -= l * 6912;
    unsigned short* wtl = wt + (size_t)l * 7077888;
    const float* src; unsigned short* dst; int Kd, Nd, nt, kt;
    if (id < 2304) {
        int m = id / 576, r = id % 576;
        src = ((m == 0) ? wq : (m == 1) ? wk : (m == 2) ? wv : wo) + (size_t)l * DM * DM;
        dst = wtl + (size_t)m * 589824;
        Kd = 768; Nd = 768; nt = r / 24; kt = r % 24;
    } else if (id < 4608) {
        int r = id - 2304;
        src = w1 + (size_t)l * DM * DFF; dst = wtl + 2359296; Kd = 768; Nd = 3072;
        nt = r / 24; kt = r % 24;
    } else {
        int r = id - 4608;
        src = w2 + (size_t)l * DFF * DM; dst = wtl + 4718592; Kd = 3072; Nd = 768;
        nt = r / 96; kt = r % 96;
    }
    int n0 = nt * 32, k0 = kt * 32;
    int c = threadIdx.x & 31, rr = threadIdx.x >> 5;
#pragma unroll
    for (int i = 0; i < 32; i += 8)
        tile[rr + i][c] = src[(size_t)(k0 + rr + i) * Nd + n0 + c];
    __syncthreads();
#pragma unroll
    for (int i = 0; i < 32; i += 8)
        dst[(size_t)(n0 + rr + i) * Kd + k0 + c] = f2bf(tile[c][rr + i]);
}

// ---------------- V transpose: vb[b*S+s][DM] bf16 -> vt[b][DM][S] bf16 ------
__global__ __launch_bounds__(256) void transpose_v(
    const unsigned short* __restrict__ vb, unsigned short* __restrict__ vt)
{
    __shared__ unsigned short tile[32][33];
    int c0 = blockIdx.x * 32;
    int r0 = blockIdx.y * 32;
    int c = threadIdx.x & 31, rr = threadIdx.x >> 5;
#pragma unroll
    for (int i = 0; i < 32; i += 8)
        tile[rr + i][c] = vb[(size_t)(r0 + rr + i) * DM + c0 + c];
    __syncthreads();
    int b = r0 >> 11;
    int s0 = r0 & 2047;
#pragma unroll
    for (int i = 0; i < 32; i += 8)
        vt[((size_t)b * DM + c0 + rr + i) * SS + s0 + c] = tile[c][rr + i];
}

// ---------------- MFMA GEMM: C[M,N] = A[M,K](bf16) @ Bt[N,K](bf16)^T --------
// 128x128 tile, BK=64, swizzled LDS (conflict-free ds_read_b128), 4 waves.
// OUT_MODE: 0=f32 split-K partial (blockIdx.z slice), 1=bf16, 2=bf16+relu,
//           4=bf16 into 3 consecutive [4096][768] mats
template<int OUT_MODE>
__global__ __launch_bounds__(256) void gemm_bt(
    const unsigned short* __restrict__ A, const unsigned short* __restrict__ Bt,
    const float* __restrict__ bias, void* __restrict__ Cv,
    int K, int lda, int ldb, int ldc)
{
    __shared__ unsigned short As[128 * 64];   // 16KB, 128B rows, chunk-swizzled
    __shared__ unsigned short Bs[128 * 64];   // 16KB
    const int t = threadIdx.x;
    const int row0 = blockIdx.y * 128;
    const int col0 = blockIdx.x * 128;
    const int z = (OUT_MODE == 0) ? blockIdx.z : 0;
    if (OUT_MODE == 0) { A += (size_t)z * K; Bt += (size_t)z * K; }
    const int lane = t & 63, wid = t >> 6;
    const int wr = wid >> 1, wc = wid & 1;
    const int half = lane >> 4, lr = lane & 15;
    f32x4 acc[4][4] = {};

    for (int k0 = 0; k0 < K; k0 += 64) {
        // stage A,B tiles: pre-swizzled source chunk, linear LDS dest (rule #21)
#pragma unroll
        for (int r_ = 0; r_ < 4; ++r_) {
            int o_ = r_ * 4096 + t * 16;
            int row_ = o_ >> 7;                 // 0..127
            int cp_ = (o_ >> 4) & 7;            // 16B chunk within 128B row
            int gk_ = (cp_ ^ (row_ & 7)) << 3;  // swizzled k-offset (ushorts)
            GL16(A + (size_t)(row0 + row_) * lda + k0 + gk_, (char*)As + o_);
            GL16(Bt + (size_t)(col0 + row_) * ldb + k0 + gk_, (char*)Bs + o_);
        }
        __syncthreads();
#pragma unroll
        for (int kk = 0; kk < 2; ++kk) {
            short8 a_[4], b_[4];
#pragma unroll
            for (int m = 0; m < 4; ++m) {
                int row_ = wr * 64 + m * 16 + lr;
                a_[m] = *(const short8*)&As[row_ * 64 + (((kk * 4 + half) ^ (row_ & 7)) << 3)];
            }
#pragma unroll
            for (int n = 0; n < 4; ++n) {
                int row_ = wc * 64 + n * 16 + lr;
                b_[n] = *(const short8*)&Bs[row_ * 64 + (((kk * 4 + half) ^ (row_ & 7)) << 3)];
            }
#pragma unroll
            for (int m = 0; m < 4; ++m)
#pragma unroll
                for (int n = 0; n < 4; ++n)
                    acc[m][n] = __builtin_amdgcn_mfma_f32_16x16x32_bf16(a_[m], b_[n], acc[m][n], 0, 0, 0);
        }
        __syncthreads();
    }

#pragma unroll
    for (int m = 0; m < 4; ++m) {
#pragma unroll
        for (int n = 0; n < 4; ++n) {
            const int cidx = col0 + wc * 64 + n * 16 + lr;
            const float bv = bias ? bias[cidx] : 0.0f;
#pragma unroll
            for (int j = 0; j < 4; ++j) {
                const int r = row0 + wr * 64 + m * 16 + half * 4 + j;
                float v = acc[m][n][j] + bv;
                if (OUT_MODE == 2) v = fmaxf(v, 0.0f);
                if (OUT_MODE == 0) {
                    ((float*)Cv)[((size_t)z * 4096 + r) * ldc + cidx] = v;
                } else if (OUT_MODE == 4) {
                    int mi = (cidx >= 1536) ? 2 : (cidx >= 768 ? 1 : 0);
                    int cl = cidx - mi * 768;
                    ((unsigned short*)Cv)[((size_t)mi * 4096 + r) * 768 + cl] = f2bf(v);
                } else {
                    ((unsigned short*)Cv)[(size_t)r * ldc + cidx] = f2bf(v);
                }
            }
        }
    }
}

// ---------------- fused attention v5: QBLK=64, 2-pass, P-write via L2 -------
// 768 blocks; id&7 = XCD, 3 heads/XCD (K/V L2/L3-resident). Pass A: row sums.
// Pass B: normalized E (reg rinv) -> cached P-write + PV. 80KB LDS, 2 blk/CU.
// r7 lesson: NT 16B-stride stores = partial-line HBM RMW (2.3x write amp,
// 1.29 TB/s drain, whole kernel store-bound). Cached stores let L2 merge.
__global__ __launch_bounds__(256) void attn_fused(
    const unsigned short* __restrict__ qg, const unsigned short* __restrict__ kg,
    const unsigned short* __restrict__ vt, const int* __restrict__ amask,
    float* __restrict__ attnL, unsigned short* __restrict__ cb)
{
    __shared__ unsigned short Ks[2][128 * 64];   // 2x16KB [krow][dk], swizzled
    __shared__ unsigned short Vs[2][64 * 128];   // 2x16KB [d][s], swizzled
    __shared__ unsigned short Es[64 * 128];      // 16KB [qrow][kcol]; aliased as redsum between passes

    const int t = threadIdx.x;
    const int id = blockIdx.x;              // 0..767
    const int xcd = id & 7, idx = id >> 3;  // idx 0..95
    const int bh = xcd * 3 + (idx >> 5);    // 24 heads, 3 per XCD
    const int qt = idx & 31;
    const int b = bh / NH, h = bh % NH;
    const int q0 = qt * 64;
    const int lane = t & 63, w = t >> 6;
    const int half = lane >> 4, lr = lane & 15;
    const int* am = amask + b * SS;

    // Q A-frags: afq[m][ks] -> rows q0+m*16+lr, k = ks*32 + half*8
    const unsigned short* qbase = qg + ((size_t)b * SS + q0 + lr) * DM + h * DK + half * 8;
    short8 afq[4][2];
#pragma unroll
    for (int m = 0; m < 4; ++m) {
        afq[m][0] = *(const short8*)(qbase + m * 16 * DM);
        afq[m][1] = *(const short8*)(qbase + m * 16 * DM + 32);
    }

    const unsigned short* Kg = kg + (size_t)b * SS * DM + h * DK;
    const unsigned short* Vg = vt + ((size_t)b * DM + h * DK) * SS;

#define STAGE_K(kt, buf) { \
    _Pragma("unroll") \
    for (int r_ = 0; r_ < 4; ++r_) { \
        int o_ = r_ * 4096 + t * 16; \
        int krow_ = o_ >> 7; \
        int cp_ = (o_ >> 4) & 7; \
        GL16(Kg + (size_t)((kt) * 128 + krow_) * DM + ((cp_ ^ (krow_ & 7)) << 3), (char*)Ks[buf] + o_); \
    } }
#define STAGE_V(kt, buf) { \
    _Pragma("unroll") \
    for (int r_ = 0; r_ < 4; ++r_) { \
        int o_ = r_ * 4096 + t * 16; \
        int d_ = o_ >> 8; \
        int cp_ = (o_ >> 4) & 15; \
        GL16(Vg + (size_t)d_ * SS + (kt) * 128 + ((cp_ ^ (d_ & 7)) << 3), (char*)Vs[buf] + o_); \
    } }

    // ================= pass A: row sums =================
    float vsum[4][4] = {};
    STAGE_K(0, 0);
    for (int kt = 0; kt < 16; ++kt) {
        asm volatile("s_waitcnt vmcnt(0)" ::: "memory");
        __builtin_amdgcn_s_barrier();
        if (kt < 15) STAGE_K(kt + 1, (kt + 1) & 1);
        const char* kbuf = (const char*)Ks[kt & 1];
#pragma unroll
        for (int nn = 0; nn < 2; ++nn) {
            const int krl = w * 32 + nn * 16 + lr;
            const char* kr = kbuf + krl * 128;
            const int ksw = krl & 7;
            short8 bk0 = *(const short8*)(kr + ((half ^ ksw) << 4));
            short8 bk1 = *(const short8*)(kr + (((4 + half) ^ ksw) << 4));
            const int kpos = kt * 128 + krl;
            const bool pad = (am[kpos] == 0);
#pragma unroll
            for (int m = 0; m < 4; ++m) {
                f32x4 s = {};
                s = __builtin_amdgcn_mfma_f32_16x16x32_bf16(afq[m][0], bk0, s, 0, 0, 0);
                s = __builtin_amdgcn_mfma_f32_16x16x32_bf16(afq[m][1], bk1, s, 0, 0, 0);
#pragma unroll
                for (int j = 0; j < 4; ++j) {
                    int qpos = q0 + m * 16 + half * 4 + j;
                    if (pad || (kpos > qpos))   // FAITHFUL: keep where pad||future
                        vsum[m][j] += __expf(0.125f * s[j]);
                }
            }
        }
    }
    // prefetch pass-B tile 0 while reducing (Ks[0] free: last read was kt=14)
    STAGE_K(0, 0);
    STAGE_V(0, 0);
    __syncthreads();

    // cross-lane + cross-wave reduce via Es-aliased scratch; rinv -> registers
    float* red = (float*)Es;     // [0..255]: per-wave sums, [256..319]: inv
#pragma unroll
    for (int m = 0; m < 4; ++m)
#pragma unroll
        for (int j = 0; j < 4; ++j) {
            vsum[m][j] += __shfl_xor(vsum[m][j], 1, 64);
            vsum[m][j] += __shfl_xor(vsum[m][j], 2, 64);
            vsum[m][j] += __shfl_xor(vsum[m][j], 4, 64);
            vsum[m][j] += __shfl_xor(vsum[m][j], 8, 64);
        }
    if (lr == 0) {
#pragma unroll
        for (int m = 0; m < 4; ++m)
#pragma unroll
            for (int j = 0; j < 4; ++j)
                red[w * 64 + m * 16 + half * 4 + j] = vsum[m][j];
    }
    __syncthreads();
    if (t < 64) {
        float rs = red[t] + red[64 + t] + red[128 + t] + red[192 + t];
        red[256 + t] = (rs > 0.0f) ? 1.0f / rs : 0.0f;
    }
    __syncthreads();
    float rinv[4][4];
#pragma unroll
    for (int m = 0; m < 4; ++m)
#pragma unroll
        for (int j = 0; j < 4; ++j)
            rinv[m][j] = red[256 + m * 16 + half * 4 + j];
    __syncthreads();   // rinv in regs; Es area may now be overwritten

    // ================= pass B: normalized E -> P + PV =================
    f32x4 ctxa[4] = {};
    float* ab = attnL + ((size_t)bh * SS + q0) * SS;
    for (int kt = 0; kt < 16; ++kt) {
        if (kt == 0) {
            asm volatile("s_waitcnt vmcnt(0)" ::: "memory");
        } else {
            asm volatile("s_waitcnt vmcnt(8)" ::: "memory");  // 8 stage loads done, P-stores in flight
        }
        __builtin_amdgcn_s_barrier();
        if (kt < 15) { STAGE_K(kt + 1, (kt + 1) & 1); STAGE_V(kt + 1, (kt + 1) & 1); }
        const char* kbuf = (const char*)Ks[kt & 1];
#pragma unroll
        for (int nn = 0; nn < 2; ++nn) {
            const int krl = w * 32 + nn * 16 + lr;
            const char* kr = kbuf + krl * 128;
            const int ksw = krl & 7;
            short8 bk0 = *(const short8*)(kr + ((half ^ ksw) << 4));
            short8 bk1 = *(const short8*)(kr + (((4 + half) ^ ksw) << 4));
            const int kpos = kt * 128 + krl;
            const bool pad = (am[kpos] == 0);
#pragma unroll
            for (int m = 0; m < 4; ++m) {
                f32x4 s = {};
                s = __builtin_amdgcn_mfma_f32_16x16x32_bf16(afq[m][0], bk0, s, 0, 0, 0);
                s = __builtin_amdgcn_mfma_f32_16x16x32_bf16(afq[m][1], bk1, s, 0, 0, 0);
#pragma unroll
                for (int j = 0; j < 4; ++j) {
                    int row = m * 16 + half * 4 + j;
                    int qpos = q0 + row;
                    bool keep = pad || (kpos > qpos);
                    float e = keep ? __expf(0.125f * s[j]) * rinv[m][j] : 0.0f;
                    *((unsigned short*)((char*)Es + row * 256 + ((krl * 2) ^ ((row & 7) << 4)))) = f2bf(e);
                }
            }
        }
        asm volatile("s_waitcnt lgkmcnt(0)" ::: "memory");   // E-writes visible
        __builtin_amdgcn_s_barrier();

        // PV: ctx += E[64x128] @ V[128x64]; wave w owns d-cols w*16..+15
        const char* vbuf = (const char*)Vs[kt & 1];
#pragma unroll
        for (int ks = 0; ks < 4; ++ks) {
            const int dl = w * 16 + lr;
            const int cv = ks * 4 + half;
            short8 bv = *(const short8*)(vbuf + dl * 256 + ((cv ^ (dl & 7)) << 4));
#pragma unroll
            for (int m = 0; m < 4; ++m) {
                short8 ae = *(const short8*)((const char*)Es + (m * 16 + lr) * 256 +
                                             ((ks * 64 + half * 16) ^ ((lr & 7) << 4)));
                ctxa[m] = __builtin_amdgcn_mfma_f32_16x16x32_bf16(ae, bv, ctxa[m], 0, 0, 0);
            }
        }

        // P-write: 256 threads cover 64 rows x 4 chunk-groups (32 f32 each),
        // CACHED stores (L2 merges into full lines -> no HBM write amp)
        {
            const int prow = t >> 2, pg = t & 3;
            const char* erow = (const char*)Es + prow * 256;
            const int swz = (prow & 7) << 4;
            float* drow = ab + (size_t)prow * SS + kt * 128;
#pragma unroll
            for (int c = 0; c < 4; ++c) {
                const int chunk = pg * 4 + c;
                short8 ev = *(const short8*)(erow + ((chunk * 16) ^ swz));
                float* dst = drow + chunk * 8;
                f32x4 o0, o1;
                o0[0] = bf2f((unsigned short)ev[0]); o0[1] = bf2f((unsigned short)ev[1]);
                o0[2] = bf2f((unsigned short)ev[2]); o0[3] = bf2f((unsigned short)ev[3]);
                o1[0] = bf2f((unsigned short)ev[4]); o1[1] = bf2f((unsigned short)ev[5]);
                o1[2] = bf2f((unsigned short)ev[6]); o1[3] = bf2f((unsigned short)ev[7]);
                *(f32x4*)dst = o0;
                *(f32x4*)(dst + 4) = o1;
            }
        }
    }

    // ctx write (already normalized)
#pragma unroll
    for (int m = 0; m < 4; ++m)
#pragma unroll
        for (int j = 0; j < 4; ++j) {
            int row = m * 16 + half * 4 + j;
            cb[((size_t)b * SS + q0 + row) * DM + h * DK + w * 16 + lr] = f2bf(ctxa[m][j]);
        }
#undef STAGE_K
#undef STAGE_V
}

// ------- residual add (two f32 split-K partials + opt bias) + layernorm ----
__global__ __launch_bounds__(256) void add_ln_kernel(
    const float* __restrict__ p0, const float* __restrict__ p1,
    const float* __restrict__ bias, const float* __restrict__ xin,
    const float* __restrict__ g, const float* __restrict__ bta,
    float* __restrict__ xout, unsigned short* __restrict__ xbout)
{
    int row = blockIdx.x;
    int t = threadIdx.x;
    const float* a0 = p0 + (size_t)row * DM;
    const float* a1 = p1 + (size_t)row * DM;
    const float* xr = xin + (size_t)row * DM;
    float* orow = xout + (size_t)row * DM;
    unsigned short* obr = xbout + (size_t)row * DM;
    __shared__ float red[256];
    float v[3];
    float sum = 0.0f;
#pragma unroll
    for (int i = 0; i < 3; ++i) {
        int c = t + 256 * i;
        v[i] = a0[c] + a1[c] + xr[c] + (bias ? bias[c] : 0.0f);
        sum += v[i];
    }
    red[t] = sum;
    __syncthreads();
    for (int s = 128; s > 0; s >>= 1) {
        if (t < s) red[t] += red[t + s];
        __syncthreads();
    }
    float mean = red[0] * (1.0f / DM);
    __syncthreads();
    float sq = 0.0f;
#pragma unroll
    for (int i = 0; i < 3; ++i) {
        float d = v[i] - mean;
        sq += d * d;
    }
    red[t] = sq;
    __syncthreads();
    for (int s = 128; s > 0; s >>= 1) {
        if (t < s) red[t] += red[t + s];
        __syncthreads();
    }
    float inv = 1.0f / sqrtf(red[0] * (1.0f / DM) + 1e-5f);
#pragma unroll
    for (int i = 0; i < 3; ++i) {
        int c = t + 256 * i;
        float ov = (v[i] - mean) * inv * g[c] + bta[c];
        orow[c] = ov;
        obr[c] = f2bf(ov);
    }
}

extern "C" void kernel_launch(void* const* d_in, const int* in_sizes, int n_in,
                              void* d_out, int out_size, void* d_ws, size_t ws_size,
                              hipStream_t stream)
{
    const int*   toks  = (const int*)d_in[0];
    const int*   amask = (const int*)d_in[1];
    const float* emb   = (const float*)d_in[2];
    const float* pos   = (const float*)d_in[3];
    const float* wq    = (const float*)d_in[4];
    const float* wk    = (const float*)d_in[5];
    const float* wv    = (const float*)d_in[6];
    const float* wo    = (const float*)d_in[7];
    const float* ln1g  = (const float*)d_in[8];
    const float* ln1b  = (const float*)d_in[9];
    const float* w1    = (const float*)d_in[10];
    const float* b1    = (const float*)d_in[11];
    const float* w2    = (const float*)d_in[12];
    const float* b2    = (const float*)d_in[13];
    const float* ln2g  = (const float*)d_in[14];
    const float* ln2b  = (const float*)d_in[15];

    float* out = (float*)d_out;
    char*  wsb = (char*)d_ws;

    const size_t ROWS = (size_t)BB * SS;                 // 4096
    const size_t XSZ  = ROWS * DM;                       // 3,145,728
    const size_t ATTN_L = (size_t)BB * NH * SS * SS;     // 100,663,296

    float*          x    = (float*)(wsb);                          // 12.58 MB
    unsigned short* xb   = (unsigned short*)(wsb + 12582912);      // 6.29 MB
    unsigned short* qb   = (unsigned short*)(wsb + 18874368);      // 6.29 MB (QKV out 0)
    unsigned short* kbuf = (unsigned short*)(wsb + 25165824);      // 6.29 MB (QKV out 1)
    unsigned short* vb   = (unsigned short*)(wsb + 31457280);      // 6.29 MB (QKV out 2)
    unsigned short* cb   = (unsigned short*)(wsb + 37748736);      // 6.29 MB
    float*          p0   = (float*)(wsb + 44040192);               // 25.17 MB (2 split-K slabs)
    unsigned short* vt   = (unsigned short*)(wsb + 69206016);      // aliases ffb
    unsigned short* ffb  = (unsigned short*)(wsb + 69206016);      // 25.17 MB
    unsigned short* wt   = (unsigned short*)(wsb + 94371840);      // 28.31 MB (both layers)

    float* attn_out = out + XSZ;

    embed_kernel<<<ROWS, 256, 0, stream>>>(toks, emb, pos, x, xb);
    prep_weights<<<13824, 256, 0, stream>>>(wq, wk, wv, wo, w1, w2, wt);

    for (int l = 0; l < NL; ++l) {
        unsigned short* QKVT = wt + (size_t)l * 7077888;
        unsigned short* WOT  = QKVT + 1769472;
        unsigned short* W1T  = QKVT + 2359296;
        unsigned short* W2T  = QKVT + 4718592;

        // merged QKV projection: N=2304 -> qb | kbuf | vb (row-major bf16)
        gemm_bt<4><<<dim3(18, 32), 256, 0, stream>>>(xb, QKVT, nullptr, qb, DM, DM, DM, DM);
        transpose_v<<<dim3(24, 128), 256, 0, stream>>>(vb, vt);

        float* attnL = attn_out + (size_t)l * ATTN_L;
        attn_fused<<<768, 256, 0, stream>>>(qb, kbuf, vt, amask, attnL, cb);

        // output projection (split-K=2, f32 partials) + LN1
        gemm_bt<0><<<dim3(6, 32, 2), 256, 0, stream>>>(cb, WOT, nullptr, p0, 384, DM, DM, DM);
        add_ln_kernel<<<ROWS, 256, 0, stream>>>(p0, p0 + XSZ, nullptr, x,
                                                ln1g + l * DM, ln1b + l * DM, x, xb);

        // FFN: W1+relu, W2 (split-K=2) + LN2 (bias b2 folded into LN)
        gemm_bt<2><<<dim3(24, 32), 256, 0, stream>>>(xb, W1T, b1 + (size_t)l * DFF, ffb, DM, DM, DM, DFF);
        gemm_bt<0><<<dim3(6, 32, 2), 256, 0, stream>>>(ffb, W2T, nullptr, p0, 1536, DFF, DFF, DM);

        float* xdst = (l == NL - 1) ? out : x;
        add_ln_kernel<<<ROWS, 256, 0, stream>>>(p0, p0 + XSZ, b2 + (size_t)l * DM, x,
                                                ln2g + l * DM, ln2b + l * DM, xdst, xb);
    }
}

// Round 9
// 740.409 us; speedup vs baseline: 2.4283x; 1.0264x over previous
//
#include <hip/hip_runtime.h>
#include <math.h>

#define DM 768
#define NH 12
#define DK 64
#define DFF 3072
#define BB 2
#define SS 2048
#define NL 2

typedef __attribute__((ext_vector_type(8))) short short8;
typedef __attribute__((ext_vector_type(4))) float f32x4;

__device__ inline unsigned short f2bf(float f) {
    unsigned int u = __float_as_uint(f);
    u += 0x7fffu + ((u >> 16) & 1u);
    return (unsigned short)(u >> 16);
}
__device__ inline float bf2f(unsigned short h) {
    return __uint_as_float(((unsigned int)h) << 16);
}

#define GL16(g, l) __builtin_amdgcn_global_load_lds( \
    (const __attribute__((address_space(1))) void*)(g), \
    (__attribute__((address_space(3))) void*)(l), 16, 0, 0)

// ---------------- embed + positional (f32 + bf16 outputs) ----------------
__global__ __launch_bounds__(256) void embed_kernel(
    const int* __restrict__ toks, const float* __restrict__ emb,
    const float* __restrict__ pos, float* __restrict__ x,
    unsigned short* __restrict__ xb)
{
    int rs = blockIdx.x;
    int s = rs & (SS - 1);
    int tok = toks[rs];
    int t = threadIdx.x;
    const float* e = emb + (size_t)tok * DM;
    const float* p = pos + (size_t)s * DM;
    float* xr = x + (size_t)rs * DM;
    unsigned short* xbr = xb + (size_t)rs * DM;
#pragma unroll
    for (int i = 0; i < 3; ++i) {
        int c = t + 256 * i;
        float v = e[c] + p[c];
        xr[c] = v;
        xbr[c] = f2bf(v);
    }
}

// ---------------- batched weight transpose-convert, BOTH layers, 1 launch ---
__global__ __launch_bounds__(256) void prep_weights(
    const float* __restrict__ wq, const float* __restrict__ wk,
    const float* __restrict__ wv, const float* __restrict__ wo,
    const float* __restrict__ w1, const float* __restrict__ w2,
    unsigned short* __restrict__ wt)
{
    __shared__ float tile[32][33];
    int id = blockIdx.x;
    int l = id / 6912; id -= l * 6912;
    unsigned short* wtl = wt + (size_t)l * 7077888;
    const float* src; unsigned short* dst; int Kd, Nd, nt, kt;
    if (id < 2304) {
        int m = id / 576, r = id % 576;
        src = ((m == 0) ? wq : (m == 1) ? wk : (m == 2) ? wv : wo) + (size_t)l * DM * DM;
        dst = wtl + (size_t)m * 589824;
        Kd = 768; Nd = 768; nt = r / 24; kt = r % 24;
    } else if (id < 4608) {
        int r = id - 2304;
        src = w1 + (size_t)l * DM * DFF; dst = wtl + 2359296; Kd = 768; Nd = 3072;
        nt = r / 24; kt = r % 24;
    } else {
        int r = id - 4608;
        src = w2 + (size_t)l * DFF * DM; dst = wtl + 4718592; Kd = 3072; Nd = 768;
        nt = r / 96; kt = r % 96;
    }
    int n0 = nt * 32, k0 = kt * 32;
    int c = threadIdx.x & 31, rr = threadIdx.x >> 5;
#pragma unroll
    for (int i = 0; i < 32; i += 8)
        tile[rr + i][c] = src[(size_t)(k0 + rr + i) * Nd + n0 + c];
    __syncthreads();
#pragma unroll
    for (int i = 0; i < 32; i += 8)
        dst[(size_t)(n0 + rr + i) * Kd + k0 + c] = f2bf(tile[c][rr + i]);
}

// ---------------- V transpose: vb[b*S+s][DM] bf16 -> vt[b][DM][S] bf16 ------
__global__ __launch_bounds__(256) void transpose_v(
    const unsigned short* __restrict__ vb, unsigned short* __restrict__ vt)
{
    __shared__ unsigned short tile[32][33];
    int c0 = blockIdx.x * 32;
    int r0 = blockIdx.y * 32;
    int c = threadIdx.x & 31, rr = threadIdx.x >> 5;
#pragma unroll
    for (int i = 0; i < 32; i += 8)
        tile[rr + i][c] = vb[(size_t)(r0 + rr + i) * DM + c0 + c];
    __syncthreads();
    int b = r0 >> 11;
    int s0 = r0 & 2047;
#pragma unroll
    for (int i = 0; i < 32; i += 8)
        vt[((size_t)b * DM + c0 + rr + i) * SS + s0 + c] = tile[c][rr + i];
}

// ---------------- MFMA GEMM: C[M,N] = A[M,K](bf16) @ Bt[N,K](bf16)^T --------
// 128x128 tile, BK=64, swizzled LDS (conflict-free ds_read_b128), 4 waves.
// OUT_MODE: 0=f32 split-K partial (blockIdx.z slice), 1=bf16, 2=bf16+relu,
//           4=bf16 into 3 consecutive [4096][768] mats
template<int OUT_MODE>
__global__ __launch_bounds__(256) void gemm_bt(
    const unsigned short* __restrict__ A, const unsigned short* __restrict__ Bt,
    const float* __restrict__ bias, void* __restrict__ Cv,
    int K, int lda, int ldb, int ldc)
{
    __shared__ unsigned short As[128 * 64];   // 16KB, 128B rows, chunk-swizzled
    __shared__ unsigned short Bs[128 * 64];   // 16KB
    const int t = threadIdx.x;
    const int row0 = blockIdx.y * 128;
    const int col0 = blockIdx.x * 128;
    const int z = (OUT_MODE == 0) ? blockIdx.z : 0;
    if (OUT_MODE == 0) { A += (size_t)z * K; Bt += (size_t)z * K; }
    const int lane = t & 63, wid = t >> 6;
    const int wr = wid >> 1, wc = wid & 1;
    const int half = lane >> 4, lr = lane & 15;
    f32x4 acc[4][4] = {};

    for (int k0 = 0; k0 < K; k0 += 64) {
        // stage A,B tiles: pre-swizzled source chunk, linear LDS dest (rule #21)
#pragma unroll
        for (int r_ = 0; r_ < 4; ++r_) {
            int o_ = r_ * 4096 + t * 16;
            int row_ = o_ >> 7;                 // 0..127
            int cp_ = (o_ >> 4) & 7;            // 16B chunk within 128B row
            int gk_ = (cp_ ^ (row_ & 7)) << 3;  // swizzled k-offset (ushorts)
            GL16(A + (size_t)(row0 + row_) * lda + k0 + gk_, (char*)As + o_);
            GL16(Bt + (size_t)(col0 + row_) * ldb + k0 + gk_, (char*)Bs + o_);
        }
        __syncthreads();
#pragma unroll
        for (int kk = 0; kk < 2; ++kk) {
            short8 a_[4], b_[4];
#pragma unroll
            for (int m = 0; m < 4; ++m) {
                int row_ = wr * 64 + m * 16 + lr;
                a_[m] = *(const short8*)&As[row_ * 64 + (((kk * 4 + half) ^ (row_ & 7)) << 3)];
            }
#pragma unroll
            for (int n = 0; n < 4; ++n) {
                int row_ = wc * 64 + n * 16 + lr;
                b_[n] = *(const short8*)&Bs[row_ * 64 + (((kk * 4 + half) ^ (row_ & 7)) << 3)];
            }
#pragma unroll
            for (int m = 0; m < 4; ++m)
#pragma unroll
                for (int n = 0; n < 4; ++n)
                    acc[m][n] = __builtin_amdgcn_mfma_f32_16x16x32_bf16(a_[m], b_[n], acc[m][n], 0, 0, 0);
        }
        __syncthreads();
    }

#pragma unroll
    for (int m = 0; m < 4; ++m) {
#pragma unroll
        for (int n = 0; n < 4; ++n) {
            const int cidx = col0 + wc * 64 + n * 16 + lr;
            const float bv = bias ? bias[cidx] : 0.0f;
#pragma unroll
            for (int j = 0; j < 4; ++j) {
                const int r = row0 + wr * 64 + m * 16 + half * 4 + j;
                float v = acc[m][n][j] + bv;
                if (OUT_MODE == 2) v = fmaxf(v, 0.0f);
                if (OUT_MODE == 0) {
                    ((float*)Cv)[((size_t)z * 4096 + r) * ldc + cidx] = v;
                } else if (OUT_MODE == 4) {
                    int mi = (cidx >= 1536) ? 2 : (cidx >= 768 ? 1 : 0);
                    int cl = cidx - mi * 768;
                    ((unsigned short*)Cv)[((size_t)mi * 4096 + r) * 768 + cl] = f2bf(v);
                } else {
                    ((unsigned short*)Cv)[(size_t)r * ldc + cidx] = f2bf(v);
                }
            }
        }
    }
}

// ---------------- fused attention v6: K direct-global, 48KB LDS, 3 blk/CU ---
// 768 blocks = 3/CU exactly (no tail); id&7 = XCD, 3 heads/XCD.
// Pass A: BARRIER-FREE row sums (K fragments are per-lane 16B reads from L2).
// Pass B: V staged dbuf (counted vmcnt), Es in LDS, cached P-writes (r8).
__global__ __launch_bounds__(256) void attn_fused(
    const unsigned short* __restrict__ qg, const unsigned short* __restrict__ kg,
    const unsigned short* __restrict__ vt, const int* __restrict__ amask,
    float* __restrict__ attnL, unsigned short* __restrict__ cb)
{
    __shared__ unsigned short Vs[2][64 * 128];   // 2x16KB [d][s], swizzled
    __shared__ unsigned short Es[64 * 128];      // 16KB [qrow][kcol]; aliased as red scratch

    const int t = threadIdx.x;
    const int id = blockIdx.x;              // 0..767
    const int xcd = id & 7, idx = id >> 3;  // idx 0..95
    const int bh = xcd * 3 + (idx >> 5);    // 24 heads, 3 per XCD
    const int qt = idx & 31;
    const int b = bh / NH, h = bh % NH;
    const int q0 = qt * 64;
    const int lane = t & 63, w = t >> 6;
    const int half = lane >> 4, lr = lane & 15;
    const int* am = amask + b * SS;

    // Q A-frags: afq[m][ks] -> rows q0+m*16+lr, k = ks*32 + half*8
    const unsigned short* qbase = qg + ((size_t)b * SS + q0 + lr) * DM + h * DK + half * 8;
    short8 afq[4][2];
#pragma unroll
    for (int m = 0; m < 4; ++m) {
        afq[m][0] = *(const short8*)(qbase + m * 16 * DM);
        afq[m][1] = *(const short8*)(qbase + m * 16 * DM + 32);
    }

    const unsigned short* Kg = kg + (size_t)b * SS * DM + h * DK;
    const unsigned short* Vg = vt + ((size_t)b * DM + h * DK) * SS;

#define STAGE_V(kt, buf) { \
    _Pragma("unroll") \
    for (int r_ = 0; r_ < 4; ++r_) { \
        int o_ = r_ * 4096 + t * 16; \
        int d_ = o_ >> 8; \
        int cp_ = (o_ >> 4) & 15; \
        GL16(Vg + (size_t)d_ * SS + (kt) * 128 + ((cp_ ^ (d_ & 7)) << 3), (char*)Vs[buf] + o_); \
    } }

    // ======== pass A: row sums — barrier-free, K fragments direct from L2 ===
    float vsum[4][4] = {};
    for (int kt = 0; kt < 16; ++kt) {
#pragma unroll
        for (int nn = 0; nn < 2; ++nn) {
            const int kpos = kt * 128 + w * 32 + nn * 16 + lr;
            const unsigned short* kr = Kg + (size_t)kpos * DM;
            short8 bk0 = *(const short8*)(kr + half * 8);
            short8 bk1 = *(const short8*)(kr + 32 + half * 8);
            const bool pad = (am[kpos] == 0);
#pragma unroll
            for (int m = 0; m < 4; ++m) {
                f32x4 s = {};
                s = __builtin_amdgcn_mfma_f32_16x16x32_bf16(afq[m][0], bk0, s, 0, 0, 0);
                s = __builtin_amdgcn_mfma_f32_16x16x32_bf16(afq[m][1], bk1, s, 0, 0, 0);
#pragma unroll
                for (int j = 0; j < 4; ++j) {
                    int qpos = q0 + m * 16 + half * 4 + j;
                    if (pad || (kpos > qpos))   // FAITHFUL: keep where pad||future
                        vsum[m][j] += __expf(0.125f * s[j]);
                }
            }
        }
    }
    // prefetch pass-B V tile 0 while reducing
    STAGE_V(0, 0);
    __syncthreads();

    // cross-lane + cross-wave reduce via Es-aliased scratch; rinv -> registers
    float* red = (float*)Es;     // [0..255]: per-wave sums, [256..319]: inv
#pragma unroll
    for (int m = 0; m < 4; ++m)
#pragma unroll
        for (int j = 0; j < 4; ++j) {
            vsum[m][j] += __shfl_xor(vsum[m][j], 1, 64);
            vsum[m][j] += __shfl_xor(vsum[m][j], 2, 64);
            vsum[m][j] += __shfl_xor(vsum[m][j], 4, 64);
            vsum[m][j] += __shfl_xor(vsum[m][j], 8, 64);
        }
    if (lr == 0) {
#pragma unroll
        for (int m = 0; m < 4; ++m)
#pragma unroll
            for (int j = 0; j < 4; ++j)
                red[w * 64 + m * 16 + half * 4 + j] = vsum[m][j];
    }
    __syncthreads();
    if (t < 64) {
        float rs = red[t] + red[64 + t] + red[128 + t] + red[192 + t];
        red[256 + t] = (rs > 0.0f) ? 1.0f / rs : 0.0f;
    }
    __syncthreads();
    float rinv[4][4];
#pragma unroll
    for (int m = 0; m < 4; ++m)
#pragma unroll
        for (int j = 0; j < 4; ++j)
            rinv[m][j] = red[256 + m * 16 + half * 4 + j];
    __syncthreads();   // rinv in regs; Es area may now be overwritten

    // ================= pass B: normalized E -> P + PV =================
    f32x4 ctxa[4] = {};
    float* ab = attnL + ((size_t)bh * SS + q0) * SS;
    for (int kt = 0; kt < 16; ++kt) {
        if (kt == 0) {
            asm volatile("s_waitcnt vmcnt(0)" ::: "memory");
        } else {
            asm volatile("s_waitcnt vmcnt(8)" ::: "memory");  // drain 4 V loads; P-stores stay in flight
        }
        __builtin_amdgcn_s_barrier();

        // K fragments + mask FIRST (so compiler's K-use wait leaves V prefetch in flight)
        short8 bk[2][2];
        bool pad[2];
#pragma unroll
        for (int nn = 0; nn < 2; ++nn) {
            const int kpos = kt * 128 + w * 32 + nn * 16 + lr;
            const unsigned short* kr = Kg + (size_t)kpos * DM;
            bk[nn][0] = *(const short8*)(kr + half * 8);
            bk[nn][1] = *(const short8*)(kr + 32 + half * 8);
            pad[nn] = (am[kpos] == 0);
        }
        __builtin_amdgcn_sched_barrier(0);
        if (kt < 15) STAGE_V(kt + 1, (kt + 1) & 1);

#pragma unroll
        for (int nn = 0; nn < 2; ++nn) {
            const int krl = w * 32 + nn * 16 + lr;
            const int kpos = kt * 128 + krl;
#pragma unroll
            for (int m = 0; m < 4; ++m) {
                f32x4 s = {};
                s = __builtin_amdgcn_mfma_f32_16x16x32_bf16(afq[m][0], bk[nn][0], s, 0, 0, 0);
                s = __builtin_amdgcn_mfma_f32_16x16x32_bf16(afq[m][1], bk[nn][1], s, 0, 0, 0);
#pragma unroll
                for (int j = 0; j < 4; ++j) {
                    int row = m * 16 + half * 4 + j;
                    int qpos = q0 + row;
                    bool keep = pad[nn] || (kpos > qpos);
                    float e = keep ? __expf(0.125f * s[j]) * rinv[m][j] : 0.0f;
                    *((unsigned short*)((char*)Es + row * 256 + ((krl * 2) ^ ((row & 7) << 4)))) = f2bf(e);
                }
            }
        }
        asm volatile("s_waitcnt lgkmcnt(0)" ::: "memory");   // E-writes visible
        __builtin_amdgcn_s_barrier();

        // PV: ctx += E[64x128] @ V[128x64]; wave w owns d-cols w*16..+15
        const char* vbuf = (const char*)Vs[kt & 1];
#pragma unroll
        for (int ks = 0; ks < 4; ++ks) {
            const int dl = w * 16 + lr;
            const int cv = ks * 4 + half;
            short8 bv = *(const short8*)(vbuf + dl * 256 + ((cv ^ (dl & 7)) << 4));
#pragma unroll
            for (int m = 0; m < 4; ++m) {
                short8 ae = *(const short8*)((const char*)Es + (m * 16 + lr) * 256 +
                                             ((ks * 64 + half * 16) ^ ((lr & 7) << 4)));
                ctxa[m] = __builtin_amdgcn_mfma_f32_16x16x32_bf16(ae, bv, ctxa[m], 0, 0, 0);
            }
        }

        // P-write: 256 threads cover 64 rows x 4 chunk-groups (32 f32 each),
        // CACHED stores (r7 lesson: NT partial-line stores = 2.3x HBM write amp)
        {
            const int prow = t >> 2, pg = t & 3;
            const char* erow = (const char*)Es + prow * 256;
            const int swz = (prow & 7) << 4;
            float* drow = ab + (size_t)prow * SS + kt * 128;
#pragma unroll
            for (int c = 0; c < 4; ++c) {
                const int chunk = pg * 4 + c;
                short8 ev = *(const short8*)(erow + ((chunk * 16) ^ swz));
                float* dst = drow + chunk * 8;
                f32x4 o0, o1;
                o0[0] = bf2f((unsigned short)ev[0]); o0[1] = bf2f((unsigned short)ev[1]);
                o0[2] = bf2f((unsigned short)ev[2]); o0[3] = bf2f((unsigned short)ev[3]);
                o1[0] = bf2f((unsigned short)ev[4]); o1[1] = bf2f((unsigned short)ev[5]);
                o1[2] = bf2f((unsigned short)ev[6]); o1[3] = bf2f((unsigned short)ev[7]);
                *(f32x4*)dst = o0;
                *(f32x4*)(dst + 4) = o1;
            }
        }
    }

    // ctx write (already normalized)
#pragma unroll
    for (int m = 0; m < 4; ++m)
#pragma unroll
        for (int j = 0; j < 4; ++j) {
            int row = m * 16 + half * 4 + j;
            cb[((size_t)b * SS + q0 + row) * DM + h * DK + w * 16 + lr] = f2bf(ctxa[m][j]);
        }
#undef STAGE_V
}

// ------- residual add (two f32 split-K partials + opt bias) + layernorm ----
__global__ __launch_bounds__(256) void add_ln_kernel(
    const float* __restrict__ p0, const float* __restrict__ p1,
    const float* __restrict__ bias, const float* __restrict__ xin,
    const float* __restrict__ g, const float* __restrict__ bta,
    float* __restrict__ xout, unsigned short* __restrict__ xbout)
{
    int row = blockIdx.x;
    int t = threadIdx.x;
    const float* a0 = p0 + (size_t)row * DM;
    const float* a1 = p1 + (size_t)row * DM;
    const float* xr = xin + (size_t)row * DM;
    float* orow = xout + (size_t)row * DM;
    unsigned short* obr = xbout + (size_t)row * DM;
    __shared__ float red[256];
    float v[3];
    float sum = 0.0f;
#pragma unroll
    for (int i = 0; i < 3; ++i) {
        int c = t + 256 * i;
        v[i] = a0[c] + a1[c] + xr[c] + (bias ? bias[c] : 0.0f);
        sum += v[i];
    }
    red[t] = sum;
    __syncthreads();
    for (int s = 128; s > 0; s >>= 1) {
        if (t < s) red[t] += red[t + s];
        __syncthreads();
    }
    float mean = red[0] * (1.0f / DM);
    __syncthreads();
    float sq = 0.0f;
#pragma unroll
    for (int i = 0; i < 3; ++i) {
        float d = v[i] - mean;
        sq += d * d;
    }
    red[t] = sq;
    __syncthreads();
    for (int s = 128; s > 0; s >>= 1) {
        if (t < s) red[t] += red[t + s];
        __syncthreads();
    }
    float inv = 1.0f / sqrtf(red[0] * (1.0f / DM) + 1e-5f);
#pragma unroll
    for (int i = 0; i < 3; ++i) {
        int c = t + 256 * i;
        float ov = (v[i] - mean) * inv * g[c] + bta[c];
        orow[c] = ov;
        obr[c] = f2bf(ov);
    }
}

extern "C" void kernel_launch(void* const* d_in, const int* in_sizes, int n_in,
                              void* d_out, int out_size, void* d_ws, size_t ws_size,
                              hipStream_t stream)
{
    const int*   toks  = (const int*)d_in[0];
    const int*   amask = (const int*)d_in[1];
    const float* emb   = (const float*)d_in[2];
    const float* pos   = (const float*)d_in[3];
    const float* wq    = (const float*)d_in[4];
    const float* wk    = (const float*)d_in[5];
    const float* wv    = (const float*)d_in[6];
    const float* wo    = (const float*)d_in[7];
    const float* ln1g  = (const float*)d_in[8];
    const float* ln1b  = (const float*)d_in[9];
    const float* w1    = (const float*)d_in[10];
    const float* b1    = (const float*)d_in[11];
    const float* w2    = (const float*)d_in[12];
    const float* b2    = (const float*)d_in[13];
    const float* ln2g  = (const float*)d_in[14];
    const float* ln2b  = (const float*)d_in[15];

    float* out = (float*)d_out;
    char*  wsb = (char*)d_ws;

    const size_t ROWS = (size_t)BB * SS;                 // 4096
    const size_t XSZ  = ROWS * DM;                       // 3,145,728
    const size_t ATTN_L = (size_t)BB * NH * SS * SS;     // 100,663,296

    float*          x    = (float*)(wsb);                          // 12.58 MB
    unsigned short* xb   = (unsigned short*)(wsb + 12582912);      // 6.29 MB
    unsigned short* qb   = (unsigned short*)(wsb + 18874368);      // 6.29 MB (QKV out 0)
    unsigned short* kbuf = (unsigned short*)(wsb + 25165824);      // 6.29 MB (QKV out 1)
    unsigned short* vb   = (unsigned short*)(wsb + 31457280);      // 6.29 MB (QKV out 2)
    unsigned short* cb   = (unsigned short*)(wsb + 37748736);      // 6.29 MB
    float*          p0   = (float*)(wsb + 44040192);               // 25.17 MB (2 split-K slabs)
    unsigned short* vt   = (unsigned short*)(wsb + 69206016);      // aliases ffb
    unsigned short* ffb  = (unsigned short*)(wsb + 69206016);      // 25.17 MB
    unsigned short* wt   = (unsigned short*)(wsb + 94371840);      // 28.31 MB (both layers)

    float* attn_out = out + XSZ;

    embed_kernel<<<ROWS, 256, 0, stream>>>(toks, emb, pos, x, xb);
    prep_weights<<<13824, 256, 0, stream>>>(wq, wk, wv, wo, w1, w2, wt);

    for (int l = 0; l < NL; ++l) {
        unsigned short* QKVT = wt + (size_t)l * 7077888;
        unsigned short* WOT  = QKVT + 1769472;
        unsigned short* W1T  = QKVT + 2359296;
        unsigned short* W2T  = QKVT + 4718592;

        // merged QKV projection: N=2304 -> qb | kbuf | vb (row-major bf16)
        gemm_bt<4><<<dim3(18, 32), 256, 0, stream>>>(xb, QKVT, nullptr, qb, DM, DM, DM, DM);
        transpose_v<<<dim3(24, 128), 256, 0, stream>>>(vb, vt);

        float* attnL = attn_out + (size_t)l * ATTN_L;
        attn_fused<<<768, 256, 0, stream>>>(qb, kbuf, vt, amask, attnL, cb);

        // output projection (split-K=2, f32 partials) + LN1
        gemm_bt<0><<<dim3(6, 32, 2), 256, 0, stream>>>(cb, WOT, nullptr, p0, 384, DM, DM, DM);
        add_ln_kernel<<<ROWS, 256, 0, stream>>>(p0, p0 + XSZ, nullptr, x,
                                                ln1g + l * DM, ln1b + l * DM, x, xb);

        // FFN: W1+relu, W2 (split-K=2) + LN2 (bias b2 folded into LN)
        gemm_bt<2><<<dim3(24, 32), 256, 0, stream>>>(xb, W1T, b1 + (size_t)l * DFF, ffb, DM, DM, DM, DFF);
        gemm_bt<0><<<dim3(6, 32, 2), 256, 0, stream>>>(ffb, W2T, nullptr, p0, 1536, DFF, DFF, DM);

        float* xdst = (l == NL - 1) ? out : x;
        add_ln_kernel<<<ROWS, 256, 0, stream>>>(p0, p0 + XSZ, b2 + (size_t)l * DM, x,
                                                ln2g + l * DM, ln2b + l * DM, xdst, xb);
    }
}